// Round 9
// baseline (219.804 us; speedup 1.0000x reference)
//
#include <hip/hip_runtime.h>
#include <cstdint>

typedef unsigned short u16;
typedef __attribute__((ext_vector_type(8))) short s16x8;
typedef __attribute__((ext_vector_type(8))) unsigned short u16x8;
typedef __attribute__((ext_vector_type(4))) float f32x4;
typedef __attribute__((ext_vector_type(16))) float f32x16;
typedef __attribute__((ext_vector_type(2))) unsigned uint2v;
typedef __attribute__((ext_vector_type(4))) unsigned uint4v;

#define CKF 0.18033688011f  // log2(e)/8, folded into Q projection

__device__ inline u16 f2bf(float f){
  union { float f; uint32_t u; } v; v.f = f;
  uint32_t r = v.u + 0x7fffu + ((v.u >> 16) & 1u);
  return (u16)(r >> 16);
}

__device__ inline f32x4 mfma16(s16x8 a, s16x8 b, f32x4 c){
  return __builtin_amdgcn_mfma_f32_16x16x32_bf16(a, b, c, 0, 0, 0);
}
__device__ inline f32x16 mfma32(s16x8 a, s16x8 b, f32x16 c){
  return __builtin_amdgcn_mfma_f32_32x32x16_bf16(a, b, c, 0, 0, 0);
}
__device__ inline unsigned cvtpk(float a, float b){
  unsigned r;
  asm("v_cvt_pk_bf16_f32 %0, %1, %2" : "=v"(r) : "v"(a), "v"(b));
  return r;
}
__device__ inline float exp2a(float x){
  float r;
  asm("v_exp_f32 %0, %1" : "=v"(r) : "v"(x));
  return r;
}
__device__ inline void glds16(const u16* g, u16* l){
  __builtin_amdgcn_global_load_lds((const __attribute__((address_space(1))) void*)g,
                                   (__attribute__((address_space(3))) void*)l, 16, 0, 0);
}
__device__ inline void glds4(const unsigned* g, unsigned* l){
  __builtin_amdgcn_global_load_lds((const __attribute__((address_space(1))) void*)g,
                                   (__attribute__((address_space(3))) void*)l, 4, 0, 0);
}

// ---------------------------------------------------------------- merged prep:
// blocks [0,6144): convert q/k/v -> bf16 ; [6144,10240): transpose+convert weights ;
// [10240,43008): pack mask bits ; [43008,43024): ctx = mc @ Wc + bc
struct PrepParams {
  const float* q; const float* k; const float* v;
  const int* mask; const float* mc;
  const float* W0; const float* W1; const float* W2; const float* W3;
  const float* Wc; const float* bc;
  u16* qo; u16* ko; u16* vo;
  u16* T0; u16* T1; u16* T2; u16* T3;
  unsigned* bits; float* ctx;
};

__global__ __launch_bounds__(256) void prep_kernel(PrepParams PP){
  __shared__ float shf[1056];
  int blk = blockIdx.x, tid = threadIdx.x;
  if (blk < 6144){
    int byy = blk >> 11, bxx = blk & 2047;
    const float* src = (byy == 0) ? PP.q : (byy == 1) ? PP.k : PP.v;
    u16* dst = (byy == 0) ? PP.qo : (byy == 1) ? PP.ko : PP.vo;
    size_t i = ((size_t)bxx * 256 + tid) * 8;
    float4 a = *(const float4*)(src + i);
    float4 b = *(const float4*)(src + i + 4);
    u16x8 o = { f2bf(a.x), f2bf(a.y), f2bf(a.z), f2bf(a.w),
                f2bf(b.x), f2bf(b.y), f2bf(b.z), f2bf(b.w) };
    *(u16x8*)(dst + i) = o;
  } else if (blk < 10240){
    int idx = blk - 6144;
    int bxx = idx & 31, byy = (idx >> 5) & 31, bzz = idx >> 10;
    const float* W = (bzz == 0) ? PP.W0 : (bzz == 1) ? PP.W1 : (bzz == 2) ? PP.W2 : PP.W3;
    u16* T = (bzz == 0) ? PP.T0 : (bzz == 1) ? PP.T1 : (bzz == 2) ? PP.T2 : PP.T3;
    float (*t)[33] = (float(*)[33])shf;
    int n0 = bxx * 32, k0 = byy * 32;
    int tx = tid & 31, ty = tid >> 5;
    #pragma unroll
    for (int j = 0; j < 4; j++)
      t[ty + j*8][tx] = W[(size_t)(k0 + ty + j*8) * 1024 + n0 + tx];
    __syncthreads();
    #pragma unroll
    for (int j = 0; j < 4; j++)
      T[(size_t)(n0 + ty + j*8) * 1024 + k0 + tx] = f2bf(t[tx][ty + j*8]);
  } else if (blk < 43008){
    size_t i = (size_t)(blk - 10240) * 256 + tid;
    int v = PP.mask[i];
    unsigned long long bal = __ballot(v != 0);
    int lane = tid & 63;
    if (lane == 0)       PP.bits[i >> 5] = (unsigned)bal;
    else if (lane == 32) PP.bits[i >> 5] = (unsigned)(bal >> 32);
  } else {
    int cb = blk - 43008;
    int c = tid & 63, kk = tid >> 6;
    int col = cb * 64 + c;
    float a0 = 0.f, a1 = 0.f;
    for (int k = kk * 256; k < kk * 256 + 256; k++){
      float wv = PP.Wc[(size_t)k * 1024 + col];
      a0 += PP.mc[k] * wv;
      a1 += PP.mc[1024 + k] * wv;
    }
    float* red = shf;  // [2][4][64]
    red[(0*4 + kk)*64 + c] = a0;
    red[(1*4 + kk)*64 + c] = a1;
    __syncthreads();
    if (tid < 64){
      int cc = tid;
      PP.ctx[cb*64 + cc] = red[cc] + red[64+cc] + red[128+cc] + red[192+cc] + PP.bc[cb*64 + cc];
    } else if (tid < 128){
      int cc = tid - 64;
      PP.ctx[1024 + cb*64 + cc] = red[256+cc] + red[320+cc] + red[384+cc] + red[448+cc]
                                  + PP.bc[cb*64 + cc];
    }
  }
}

// ---------------------------------------------------------------- GEMM: BM=128 BN=256 BK=32,
// 4 waves (per-wave 64x128 output), dbuf counted-vmcnt, unrolled-by-2. XCD swizzle on BY.
struct GemmParams {
  const u16* A0; const u16* A1; const u16* A2; const u16* A3;
  const u16* W0; const u16* W1; const u16* W2; const u16* W3;
  const float* b0; const float* b1; const float* b2;
  const float* ctx;
  u16* outQ; u16* outK; u16* outV; float* outX0; float* outX1;
  int which;
};

__global__ __launch_bounds__(256, 2) void gemm_kernel(GemmParams P){
  // grid (4, 32, z). flat o; xcd = o&7; by = xcd + 8*(j&3), bx = (j>>2)&3, bz = j>>4.
  int o = blockIdx.x + (blockIdx.y << 2) + (blockIdx.z << 7);
  int xcd = o & 7, j = o >> 3;
  int by = xcd + ((j & 3) << 3);
  int bx = (j >> 2) & 3;
  int bz = j >> 4;

  int z, kbase, nkt;
  const u16* A; const u16* W;
  if (P.which < 0){
    z = bz; kbase = 0; nkt = 32;
    if (z == 0){ A = P.A0; W = P.W0; }
    else if (z == 1){ A = P.A1; W = P.W1; }
    else { A = P.A2; W = P.W2; }
  } else {
    z = 3; kbase = bz * 512; nkt = 16;
    A = P.A3; W = P.W3;
  }
  int m0 = by * 128, n0 = bx * 256;
  // buf ct at ct*12288 u16: A [0,4096), B [4096,12288). 48KB total; reused for z=2 transpose.
  __shared__ __align__(16) u16 sm[24576];
  int tid = threadIdx.x, lane = tid & 63, w = tid >> 6;
  int li = lane & 15, lq = lane >> 4;
  int wm = w >> 1, wn = w & 1;
  f32x4 zero = {0.f, 0.f, 0.f, 0.f};
  f32x4 acc[4][8];
  #pragma unroll
  for (int i = 0; i < 4; i++)
    #pragma unroll
    for (int jj = 0; jj < 8; jj++) acc[i][jj] = zero;

  // staging sources: 4 lanes/row (32 u16 per row), col pre-swizzled
  int scolS = ((lane & 3) ^ ((lane >> 3) & 3)) << 3;
  int rowS = w * 16 + (lane >> 2);
  const u16* aS0 = A + (size_t)(m0 + rowS) * 1024 + kbase + scolS;
  const u16* aS1 = aS0 + (size_t)64 * 1024;
  const u16* bS0 = W + (size_t)(n0 + rowS) * 1024 + kbase + scolS;
  const u16* bS1 = bS0 + (size_t)64 * 1024;
  const u16* bS2 = bS0 + (size_t)128 * 1024;
  const u16* bS3 = bS0 + (size_t)192 * 1024;
  int d0 = (w * 64) * 8, d1 = (256 + w * 64) * 8;
  int d2 = (512 + w * 64) * 8, d3 = (768 + w * 64) * 8;

  // LDS read byte offsets (loop-invariant)
  int aOff[4], bOff[8];
  #pragma unroll
  for (int mb = 0; mb < 4; mb++){
    int row = wm * 64 + mb * 16 + li;
    aOff[mb] = (row * 32 + ((lq ^ ((row >> 1) & 3)) << 3)) * 2;
  }
  #pragma unroll
  for (int nb = 0; nb < 8; nb++){
    int row = wn * 128 + nb * 16 + li;
    bOff[nb] = 8192 + (row * 32 + ((lq ^ ((row >> 1) & 3)) << 3)) * 2;
  }

  auto STAGE = [&](int ct){
    u16* Ab = &sm[ct * 12288];
    u16* Bb = &sm[ct * 12288 + 4096];
    glds16(aS0, Ab + d0);
    glds16(aS1, Ab + d1);
    glds16(bS0, Bb + d0);
    glds16(bS1, Bb + d1);
    glds16(bS2, Bb + d2);
    glds16(bS3, Bb + d3);
  };
  auto ADV = [&](){ aS0 += 32; aS1 += 32; bS0 += 32; bS1 += 32; bS2 += 32; bS3 += 32; };

  auto KITER = [&](int kt, int ct){
    __builtin_amdgcn_s_barrier();
    if (kt + 1 < nkt){
      STAGE(ct ^ 1); ADV();
      asm volatile("s_waitcnt vmcnt(6)" ::: "memory");
    } else {
      asm volatile("s_waitcnt vmcnt(0)" ::: "memory");
    }
    __builtin_amdgcn_sched_barrier(0);
    __builtin_amdgcn_s_barrier();
    const char* base = (const char*)sm + ct * 24576;
    s16x8 af[4], bfr[8];
    #pragma unroll
    for (int mb = 0; mb < 4; mb++) af[mb] = *(const s16x8*)(base + aOff[mb]);
    #pragma unroll
    for (int nb = 0; nb < 8; nb++) bfr[nb] = *(const s16x8*)(base + bOff[nb]);
    __builtin_amdgcn_s_setprio(1);
    #pragma unroll
    for (int mb = 0; mb < 4; mb++)
      #pragma unroll
      for (int nb = 0; nb < 8; nb++)
        acc[mb][nb] = mfma16(af[mb], bfr[nb], acc[mb][nb]);
    __builtin_amdgcn_s_setprio(0);
  };

  STAGE(0); ADV();
  for (int kt = 0; kt < nkt; kt += 2){
    KITER(kt, 0);
    KITER(kt + 1, 1);
  }

  if (z == 2){
    const float* bias = P.b2;
    int bq_ = m0 >> 11, srow0 = m0 & 2047;
    u16* Ot = sm;
    #pragma unroll
    for (int h2 = 0; h2 < 2; h2++){
      __syncthreads();
      if (wn == h2){
        #pragma unroll
        for (int mb = 0; mb < 4; mb++){
          #pragma unroll
          for (int nb = 0; nb < 8; nb++){
            int cl = nb * 16 + li;
            int rowB = wm * 64 + mb * 16 + lq * 4;
            float bcol = bias[n0 + h2 * 128 + cl];
            unsigned p01 = cvtpk(acc[mb][nb][0] + bcol, acc[mb][nb][1] + bcol);
            unsigned p23 = cvtpk(acc[mb][nb][2] + bcol, acc[mb][nb][3] + bcol);
            int ba = cl * 256 + ((rowB * 2) ^ ((cl & 7) << 4));
            *(unsigned*)((char*)Ot + ba) = p01;
            *(unsigned*)((char*)Ot + ba + 4) = p23;
          }
        }
      }
      __syncthreads();
      #pragma unroll
      for (int i = 0; i < 8; i++){
        int u = i * 256 + tid;
        int cl = u >> 4, sc = u & 15;
        int ba = cl * 256 + ((sc * 16) ^ ((cl & 7) << 4));
        u16x8 vv = *(const u16x8*)((char*)Ot + ba);
        *(u16x8*)(P.outV + (((size_t)(bq_ * 1024 + n0 + h2 * 128 + cl)) << 11) + srow0 + sc * 8) = vv;
      }
    }
    return;
  }

  if (z == 3){
    float* Xo = (kbase == 0) ? P.outX0 : P.outX1;
    #pragma unroll
    for (int mb = 0; mb < 4; mb++){
      #pragma unroll
      for (int nb = 0; nb < 8; nb++){
        int col = n0 + wn * 128 + nb * 16 + li;
        #pragma unroll
        for (int r = 0; r < 4; r++){
          int row = m0 + wm * 64 + mb * 16 + lq * 4 + r;
          Xo[(size_t)row * 1024 + col] = acc[mb][nb][r];
        }
      }
    }
    return;
  }

  const float* bias = (z == 0) ? P.b0 : P.b1;
  #pragma unroll
  for (int mb = 0; mb < 4; mb++){
    #pragma unroll
    for (int nb = 0; nb < 8; nb++){
      int colL = wn * 128 + nb * 16 + li; int col = n0 + colL;
      float bcol = bias[col];
      #pragma unroll
      for (int r = 0; r < 4; r++){
        int row = m0 + wm * 64 + mb * 16 + lq * 4 + r;
        float v = acc[mb][nb][r] + bcol;
        if (z == 0){
          P.outQ[(size_t)row * 1024 + col] = f2bf(v * CKF);  // fold softmax scale into Q
        } else {
          v += P.ctx[(size_t)(row >> 11) * 1024 + col];
          P.outK[(size_t)row * 1024 + col] = f2bf(v);
        }
      }
    }
  }
}

// ---------------------------------------------------------------- flash attention (unchanged from R8)
__global__ __launch_bounds__(256) void attn_kernel(
    const u16* __restrict__ Qg, const u16* __restrict__ Kg, const u16* __restrict__ Vtg,
    const unsigned* __restrict__ mbits, u16* __restrict__ ctx2){
  __shared__ __align__(16) u16 arena[17408];
  int tid = threadIdx.x, lane = tid & 63, w = tid >> 6;
  int l31 = lane & 31, hi = lane >> 5;
  int r7 = l31 & 7;
  int orig = blockIdx.x + (blockIdx.y << 4);
  int swz = (orig & 7) * 64 + (orig >> 3);
  int q0 = (swz & 15) * 128, bh = swz >> 4, b = bh >> 4, h = bh & 15;

  s16x8 qf[4];
  {
    const u16* qp = Qg + (size_t)(b * 2048 + q0 + w * 32 + l31) * 1024 + h * 64 + hi * 8;
    #pragma unroll
    for (int ks = 0; ks < 4; ks++)
      qf[ks] = *(const s16x8*)(qp + ks * 16);
  }
  s16x8 onesf;
  #pragma unroll
  for (int e = 0; e < 8; e++) onesf[e] = (short)0x3F80;  // bf16 1.0
  f32x16 ZERO;
  #pragma unroll
  for (int r = 0; r < 16; r++) ZERO[r] = 0.f;

  int scolS = ((lane & 7) ^ (lane >> 3)) << 3;
  int rowS = w * 16 + (lane >> 3);
  const u16* kS0 = Kg + (size_t)(b * 2048 + rowS) * 1024 + h * 64 + scolS;
  const u16* kS1 = kS0 + (size_t)8 * 1024;
  const u16* vS0 = Vtg + (((size_t)(bh * 64 + rowS)) << 11) + scolS;
  const u16* vS1 = vS0 + ((size_t)8 << 11);
  int um = w * 64 + lane;
  const unsigned* mS = mbits + (size_t)(b * 2048 + q0 + (um >> 1)) * 64 + (um & 1);
  int kD0 = w * 1024, kD1 = w * 1024 + 512;

  int qr = w * 32 + l31;
  int koff[2][4], voff[2][4];
  #pragma unroll
  for (int jj = 0; jj < 2; jj++)
    #pragma unroll
    for (int ks = 0; ks < 4; ks++){
      koff[jj][ks] = ((jj * 32 + l31) * 64 + (((ks * 2 + hi) ^ r7) << 3)) * 2;
      voff[jj][ks] = 8192 + ((jj * 32 + l31) * 64 + (((ks * 2 + hi) ^ r7) << 3)) * 2;
    }
  int mB = 32768 + qr * 8;

  auto STAGE = [&](int ct){
    u16* dst = &arena[ct * 8192];
    glds16(kS0, dst + kD0);
    glds16(kS1, dst + kD1);
    glds16(vS0, dst + 4096 + kD0);
    glds16(vS1, dst + 4096 + kD1);
    glds4(mS, (unsigned*)&arena[16384] + ct * 256 + w * 64);
  };
  auto ADV = [&](){
    kS0 += (size_t)64 * 1024; kS1 += (size_t)64 * 1024;
    vS0 += 64; vS1 += 64; mS += 2;
  };

  f32x16 accO[2], accS;
  #pragma unroll
  for (int d = 0; d < 2; d++) accO[d] = ZERO;
  accS = ZERO;

  STAGE(0); ADV();

  auto ITER = [&](int t, int ct){
    __builtin_amdgcn_s_barrier();
    if (t < 31){
      STAGE(ct ^ 1); ADV();
      asm volatile("s_waitcnt vmcnt(5)" ::: "memory");
    } else {
      asm volatile("s_waitcnt vmcnt(0)" ::: "memory");
    }
    __builtin_amdgcn_sched_barrier(0);
    __builtin_amdgcn_s_barrier();
    const char* base = (const char*)arena + ct * 16384;

    f32x16 S[2];
    __builtin_amdgcn_s_setprio(1);
    #pragma unroll
    for (int jj = 0; jj < 2; jj++){
      S[jj] = ZERO;
      #pragma unroll
      for (int ks = 0; ks < 4; ks++){
        s16x8 kf = *(const s16x8*)(base + koff[jj][ks]);
        S[jj] = mfma32(kf, qf[ks], S[jj]);
      }
    }
    __builtin_amdgcn_s_setprio(0);

    uint2v mw = *(const uint2v*)((const char*)arena + ct * 1024 + mB);
    unsigned mh0 = mw[0] >> (hi << 2), mh1 = mw[1] >> (hi << 2);
    #pragma unroll
    for (int jj = 0; jj < 2; jj++){
      unsigned mh = jj ? mh1 : mh0;
      #pragma unroll
      for (int rg = 0; rg < 16; rg++){
        int pos = (rg & 3) + ((rg >> 2) << 3);
        float pv = exp2a(S[jj][rg]);
        S[jj][rg] = ((mh >> pos) & 1u) ? pv : 0.f;
      }
    }

    s16x8 pf[4];
    #pragma unroll
    for (int jj = 0; jj < 2; jj++){
      #pragma unroll
      for (int hs = 0; hs < 2; hs++){
        int rb = hs * 8;
        unsigned A0 = cvtpk(S[jj][rb + 0], S[jj][rb + 1]);
        unsigned A1 = cvtpk(S[jj][rb + 2], S[jj][rb + 3]);
        unsigned B0 = cvtpk(S[jj][rb + 4], S[jj][rb + 5]);
        unsigned B1 = cvtpk(S[jj][rb + 6], S[jj][rb + 7]);
        uint2v r01 = __builtin_amdgcn_permlane32_swap(A0, B0, false, false);
        uint2v r23 = __builtin_amdgcn_permlane32_swap(A1, B1, false, false);
        uint4v uu = { r01[0], r23[0], r01[1], r23[1] };
        pf[jj * 2 + hs] = *(s16x8*)&uu;
      }
    }
    __builtin_amdgcn_s_setprio(1);
    #pragma unroll
    for (int c = 0; c < 4; c++){
      #pragma unroll
      for (int dh = 0; dh < 2; dh++){
        s16x8 vf = *(const s16x8*)(base + voff[dh][c]);
        accO[dh] = mfma32(vf, pf[c], accO[dh]);
      }
      accS = mfma32(onesf, pf[c], accS);
    }
    __builtin_amdgcn_s_setprio(0);
  };

  for (int t = 0; t < 32; t += 2){
    ITER(t, 0);
    ITER(t + 1, 1);
  }

  __syncthreads();
  float lsum = accS[0];
  float inv = 1.f / lsum;
  u16* Ot = arena;
  #pragma unroll
  for (int dh = 0; dh < 2; dh++){
    #pragma unroll
    for (int rg = 0; rg < 16; rg += 2){
      int dk = dh * 32 + (rg & 3) + ((rg >> 2) << 3) + (hi << 2);
      unsigned pk = cvtpk(accO[dh][rg] * inv, accO[dh][rg + 1] * inv);
      *(unsigned*)&Ot[qr * 64 + (((dk >> 3) ^ (qr & 7)) << 3) + (dk & 7)] = pk;
    }
  }
  __syncthreads();
  #pragma unroll
  for (int i = 0; i < 4; i++){
    int u = i * 256 + tid, row = u >> 3, slot = u & 7;
    u16x8 vv = *(const u16x8*)&Ot[row * 64 + ((slot ^ (row & 7)) << 3)];
    *(u16x8*)(ctx2 + (size_t)(b * 2048 + q0 + row) * 1024 + h * 64 + slot * 8) = vv;
  }
}

// ---------------------------------------------------------------- LayerNorm of (X0 + X1 + query + bo)
__global__ __launch_bounds__(256) void ln_kernel(const float* __restrict__ X0,
                                                 const float* __restrict__ X1,
                                                 const float* __restrict__ qres,
                                                 const float* __restrict__ bo,
                                                 const float* __restrict__ g,
                                                 const float* __restrict__ bb,
                                                 float* __restrict__ out){
  size_t row = blockIdx.x;
  int tid = threadIdx.x;
  float4 a = *(const float4*)(X0 + row * 1024 + tid * 4);
  float4 c = *(const float4*)(X1 + row * 1024 + tid * 4);
  float4 q = *(const float4*)(qres + row * 1024 + tid * 4);
  float4 bv = *(const float4*)(bo + tid * 4);
  float4 v;
  v.x = a.x + c.x + q.x + bv.x;
  v.y = a.y + c.y + q.y + bv.y;
  v.z = a.z + c.z + q.z + bv.z;
  v.w = a.w + c.w + q.w + bv.w;
  float s = v.x + v.y + v.z + v.w;
  float s2 = v.x*v.x + v.y*v.y + v.z*v.z + v.w*v.w;
  #pragma unroll
  for (int o = 1; o < 64; o <<= 1){
    s += __shfl_xor(s, o, 64);
    s2 += __shfl_xor(s2, o, 64);
  }
  __shared__ float rs[4], rs2[4];
  int w = tid >> 6;
  if ((tid & 63) == 0){ rs[w] = s; rs2[w] = s2; }
  __syncthreads();
  s = rs[0] + rs[1] + rs[2] + rs[3];
  s2 = rs2[0] + rs2[1] + rs2[2] + rs2[3];
  float mu = s * (1.f / 1024.f);
  float var = s2 * (1.f / 1024.f) - mu * mu;
  float rstd = rsqrtf(var + 1e-5f);
  float4 gg = *(const float4*)(g + tid * 4);
  float4 bt = *(const float4*)(bb + tid * 4);
  float4 o;
  o.x = (v.x - mu) * rstd * gg.x + bt.x;
  o.y = (v.y - mu) * rstd * gg.y + bt.y;
  o.z = (v.z - mu) * rstd * gg.z + bt.z;
  o.w = (v.w - mu) * rstd * gg.w + bt.w;
  *(float4*)(out + row * 1024 + tid * 4) = o;
}

// ----------------------------------------------------------------
extern "C" void kernel_launch(void* const* d_in, const int* in_sizes, int n_in,
                              void* d_out, int out_size, void* d_ws, size_t ws_size,
                              hipStream_t stream){
  const float* query = (const float*)d_in[0];
  const float* key_  = (const float*)d_in[1];
  const float* value = (const float*)d_in[2];
  const int*   mask  = (const int*)d_in[3];
  const float* mc    = (const float*)d_in[4];
  const float* Wq = (const float*)d_in[5];  const float* bq = (const float*)d_in[6];
  const float* Wk = (const float*)d_in[7];  const float* bk = (const float*)d_in[8];
  const float* Wv = (const float*)d_in[9];  const float* bv = (const float*)d_in[10];
  const float* Wo = (const float*)d_in[11]; const float* bo = (const float*)d_in[12];
  const float* Wc = (const float*)d_in[13]; const float* bc = (const float*)d_in[14];
  const float* lng = (const float*)d_in[15]; const float* lnb = (const float*)d_in[16];
  float* outp = (float*)d_out;
  uint8_t* ws = (uint8_t*)d_ws;
  const size_t MB = (size_t)1 << 20;
  if (ws_size < 58 * MB) return;

  u16* q_bf = (u16*)(ws + 0);         // dead after QKV; reused as ctx2
  u16* k_bf = (u16*)(ws + 8 * MB);
  u16* v_bf = (u16*)(ws + 16 * MB);
  float* X0 = (float*)(ws + 8 * MB);  // overlays k_bf/v_bf (dead after QKV GEMM)
  u16* Qb   = (u16*)(ws + 24 * MB);
  u16* Kb   = (u16*)(ws + 32 * MB);
  float* X1 = (float*)(ws + 32 * MB); // overlays Kb/Vt (dead after attn)
  u16* Vt   = (u16*)(ws + 40 * MB);
  u16* Wqt  = (u16*)(ws + 48 * MB);
  u16* Wkt  = (u16*)(ws + 50 * MB);
  u16* Wvt  = (u16*)(ws + 52 * MB);
  u16* Wot  = (u16*)(ws + 54 * MB);
  unsigned* mbits = (unsigned*)(ws + 56 * MB);
  float* ctxf = (float*)(ws + 57 * MB);
  u16* ctx2 = q_bf;

  PrepParams PP;
  PP.q = query; PP.k = key_; PP.v = value; PP.mask = mask; PP.mc = mc;
  PP.W0 = Wq; PP.W1 = Wk; PP.W2 = Wv; PP.W3 = Wo; PP.Wc = Wc; PP.bc = bc;
  PP.qo = q_bf; PP.ko = k_bf; PP.vo = v_bf;
  PP.T0 = Wqt; PP.T1 = Wkt; PP.T2 = Wvt; PP.T3 = Wot;
  PP.bits = mbits; PP.ctx = ctxf;
  prep_kernel<<<43024, 256, 0, stream>>>(PP);

  GemmParams gp;
  gp.A0 = q_bf; gp.A1 = k_bf; gp.A2 = v_bf; gp.A3 = ctx2;
  gp.W0 = Wqt;  gp.W1 = Wkt;  gp.W2 = Wvt;  gp.W3 = Wot;
  gp.b0 = bq;   gp.b1 = bk;   gp.b2 = bv;
  gp.ctx = ctxf;
  gp.outQ = Qb; gp.outK = Kb; gp.outV = Vt; gp.outX0 = X0; gp.outX1 = X1;
  gp.which = -1;
  gemm_kernel<<<dim3(4, 32, 3), 256, 0, stream>>>(gp);

  attn_kernel<<<dim3(16, 32), 256, 0, stream>>>(Qb, Kb, Vt, mbits, ctx2);

  gp.which = 3;
  gemm_kernel<<<dim3(4, 32, 2), 256, 0, stream>>>(gp);

  ln_kernel<<<4096, 256, 0, stream>>>(X0, X1, query, bo, lng, lnb, outp);
}

// Round 11
// 161.077 us; speedup vs baseline: 1.3646x; 1.3646x over previous
//
#include <hip/hip_runtime.h>
#include <cstdint>

typedef unsigned short u16;
typedef __attribute__((ext_vector_type(8))) short s16x8;
typedef __attribute__((ext_vector_type(8))) unsigned short u16x8;
typedef __attribute__((ext_vector_type(4))) float f32x4;
typedef __attribute__((ext_vector_type(16))) float f32x16;
typedef __attribute__((ext_vector_type(2))) unsigned uint2v;
typedef __attribute__((ext_vector_type(4))) unsigned uint4v;

#define CKF 0.18033688011f  // log2(e)/8, folded into Q projection

__device__ inline u16 f2bf(float f){
  union { float f; uint32_t u; } v; v.f = f;
  uint32_t r = v.u + 0x7fffu + ((v.u >> 16) & 1u);
  return (u16)(r >> 16);
}

__device__ inline f32x4 mfma16(s16x8 a, s16x8 b, f32x4 c){
  return __builtin_amdgcn_mfma_f32_16x16x32_bf16(a, b, c, 0, 0, 0);
}
__device__ inline f32x16 mfma32(s16x8 a, s16x8 b, f32x16 c){
  return __builtin_amdgcn_mfma_f32_32x32x16_bf16(a, b, c, 0, 0, 0);
}
__device__ inline unsigned cvtpk(float a, float b){
  unsigned r;
  asm("v_cvt_pk_bf16_f32 %0, %1, %2" : "=v"(r) : "v"(a), "v"(b));
  return r;
}
__device__ inline float exp2a(float x){
  float r;
  asm("v_exp_f32 %0, %1" : "=v"(r) : "v"(x));
  return r;
}
__device__ inline void glds16(const u16* g, u16* l){
  __builtin_amdgcn_global_load_lds((const __attribute__((address_space(1))) void*)g,
                                   (__attribute__((address_space(3))) void*)l, 16, 0, 0);
}
__device__ inline void glds4(const unsigned* g, unsigned* l){
  __builtin_amdgcn_global_load_lds((const __attribute__((address_space(1))) void*)g,
                                   (__attribute__((address_space(3))) void*)l, 4, 0, 0);
}

// ---------------------------------------------------------------- merged prep:
// [0,6144): convert q/k/v -> bf16 ; [6144,10240): transpose+convert weights ;
// [10240,43008): pack mask bits ; [43008,43024): ctx partials (16 slices x 64 k-rows, coalesced)
struct PrepParams {
  const float* q; const float* k; const float* v;
  const int* mask; const float* mc;
  const float* W0; const float* W1; const float* W2; const float* W3;
  const float* Wc;
  u16* qo; u16* ko; u16* vo;
  u16* T0; u16* T1; u16* T2; u16* T3;
  unsigned* bits; float* part;
};

__global__ __launch_bounds__(256) void prep_kernel(PrepParams PP){
  __shared__ float shf[1056];
  int blk = blockIdx.x, tid = threadIdx.x;
  if (blk < 6144){
    int byy = blk >> 11, bxx = blk & 2047;
    const float* src = (byy == 0) ? PP.q : (byy == 1) ? PP.k : PP.v;
    u16* dst = (byy == 0) ? PP.qo : (byy == 1) ? PP.ko : PP.vo;
    size_t i = ((size_t)bxx * 256 + tid) * 8;
    float4 a = *(const float4*)(src + i);
    float4 b = *(const float4*)(src + i + 4);
    u16x8 o = { f2bf(a.x), f2bf(a.y), f2bf(a.z), f2bf(a.w),
                f2bf(b.x), f2bf(b.y), f2bf(b.z), f2bf(b.w) };
    *(u16x8*)(dst + i) = o;
  } else if (blk < 10240){
    int idx = blk - 6144;
    int bxx = idx & 31, byy = (idx >> 5) & 31, bzz = idx >> 10;
    const float* W = (bzz == 0) ? PP.W0 : (bzz == 1) ? PP.W1 : (bzz == 2) ? PP.W2 : PP.W3;
    u16* T = (bzz == 0) ? PP.T0 : (bzz == 1) ? PP.T1 : (bzz == 2) ? PP.T2 : PP.T3;
    float (*t)[33] = (float(*)[33])shf;
    int n0 = bxx * 32, k0 = byy * 32;
    int tx = tid & 31, ty = tid >> 5;
    #pragma unroll
    for (int j = 0; j < 4; j++)
      t[ty + j*8][tx] = W[(size_t)(k0 + ty + j*8) * 1024 + n0 + tx];
    __syncthreads();
    #pragma unroll
    for (int j = 0; j < 4; j++)
      T[(size_t)(n0 + ty + j*8) * 1024 + k0 + tx] = f2bf(t[tx][ty + j*8]);
  } else if (blk < 43008){
    size_t i = (size_t)(blk - 10240) * 256 + tid;
    int v = PP.mask[i];
    unsigned long long bal = __ballot(v != 0);
    int lane = tid & 63;
    if (lane == 0)       PP.bits[i >> 5] = (unsigned)bal;
    else if (lane == 32) PP.bits[i >> 5] = (unsigned)(bal >> 32);
  } else {
    // ctx partials: 16 slices x 64 k-rows (covers K=1024 exactly); thread owns 4 contiguous cols.
    int slice = blk - 43008;          // 0..15
    int k0 = slice * 64;
    float4 a0 = {0.f,0.f,0.f,0.f}, a1 = {0.f,0.f,0.f,0.f};
    const float* wp = PP.Wc + (size_t)k0 * 1024 + tid * 4;
    #pragma unroll 8
    for (int k = 0; k < 64; k++){
      float4 wv = *(const float4*)(wp + (size_t)k * 1024);
      float m0 = PP.mc[k0 + k], m1 = PP.mc[1024 + k0 + k];
      a0.x += m0 * wv.x; a0.y += m0 * wv.y; a0.z += m0 * wv.z; a0.w += m0 * wv.w;
      a1.x += m1 * wv.x; a1.y += m1 * wv.y; a1.z += m1 * wv.z; a1.w += m1 * wv.w;
    }
    *(float4*)(PP.part + ((size_t)slice * 2 + 0) * 1024 + tid * 4) = a0;
    *(float4*)(PP.part + ((size_t)slice * 2 + 1) * 1024 + tid * 4) = a1;
  }
}

// ---------------------------------------------------------------- ctx reduce: ctx = sum(16 partials) + bc
__global__ __launch_bounds__(256) void ctxred_kernel(const float* __restrict__ part,
                                                     const float* __restrict__ bc,
                                                     float* __restrict__ ctx){
  int b = blockIdx.x, tid = threadIdx.x;
  float4 s = *(const float4*)(bc + tid * 4);
  #pragma unroll 4
  for (int sl = 0; sl < 16; sl++){
    float4 p = *(const float4*)(part + ((size_t)sl * 2 + b) * 1024 + tid * 4);
    s.x += p.x; s.y += p.y; s.z += p.z; s.w += p.w;
  }
  *(float4*)(ctx + (size_t)b * 1024 + tid * 4) = s;
}

// ---------------------------------------------------------------- GEMM: BM=128 BN=256 BK=32,
// 4 waves (per-wave 64x128 output), dbuf counted-vmcnt, unrolled-by-2. XCD swizzle on BY.
struct GemmParams {
  const u16* A0; const u16* A1; const u16* A2; const u16* A3;
  const u16* W0; const u16* W1; const u16* W2; const u16* W3;
  const float* b0; const float* b1; const float* b2;
  const float* ctx;
  u16* outQ; u16* outK; u16* outV; float* outX0; float* outX1;
  int which;
};

__global__ __launch_bounds__(256, 2) void gemm_kernel(GemmParams P){
  int o = blockIdx.x + (blockIdx.y << 2) + (blockIdx.z << 7);
  int xcd = o & 7, j = o >> 3;
  int by = xcd + ((j & 3) << 3);
  int bx = (j >> 2) & 3;
  int bz = j >> 4;

  int z, kbase, nkt;
  const u16* A; const u16* W;
  if (P.which < 0){
    z = bz; kbase = 0; nkt = 32;
    if (z == 0){ A = P.A0; W = P.W0; }
    else if (z == 1){ A = P.A1; W = P.W1; }
    else { A = P.A2; W = P.W2; }
  } else {
    z = 3; kbase = bz * 512; nkt = 16;
    A = P.A3; W = P.W3;
  }
  int m0 = by * 128, n0 = bx * 256;
  __shared__ __align__(16) u16 sm[24576];
  int tid = threadIdx.x, lane = tid & 63, w = tid >> 6;
  int li = lane & 15, lq = lane >> 4;
  int wm = w >> 1, wn = w & 1;
  f32x4 zero = {0.f, 0.f, 0.f, 0.f};
  f32x4 acc[4][8];
  #pragma unroll
  for (int i = 0; i < 4; i++)
    #pragma unroll
    for (int jj = 0; jj < 8; jj++) acc[i][jj] = zero;

  int scolS = ((lane & 3) ^ ((lane >> 3) & 3)) << 3;
  int rowS = w * 16 + (lane >> 2);
  const u16* aS0 = A + (size_t)(m0 + rowS) * 1024 + kbase + scolS;
  const u16* aS1 = aS0 + (size_t)64 * 1024;
  const u16* bS0 = W + (size_t)(n0 + rowS) * 1024 + kbase + scolS;
  const u16* bS1 = bS0 + (size_t)64 * 1024;
  const u16* bS2 = bS0 + (size_t)128 * 1024;
  const u16* bS3 = bS0 + (size_t)192 * 1024;
  int d0 = (w * 64) * 8, d1 = (256 + w * 64) * 8;
  int d2 = (512 + w * 64) * 8, d3 = (768 + w * 64) * 8;

  int aOff[4], bOff[8];
  #pragma unroll
  for (int mb = 0; mb < 4; mb++){
    int row = wm * 64 + mb * 16 + li;
    aOff[mb] = (row * 32 + ((lq ^ ((row >> 1) & 3)) << 3)) * 2;
  }
  #pragma unroll
  for (int nb = 0; nb < 8; nb++){
    int row = wn * 128 + nb * 16 + li;
    bOff[nb] = 8192 + (row * 32 + ((lq ^ ((row >> 1) & 3)) << 3)) * 2;
  }

  auto STAGE = [&](int ct){
    u16* Ab = &sm[ct * 12288];
    u16* Bb = &sm[ct * 12288 + 4096];
    glds16(aS0, Ab + d0);
    glds16(aS1, Ab + d1);
    glds16(bS0, Bb + d0);
    glds16(bS1, Bb + d1);
    glds16(bS2, Bb + d2);
    glds16(bS3, Bb + d3);
  };
  auto ADV = [&](){ aS0 += 32; aS1 += 32; bS0 += 32; bS1 += 32; bS2 += 32; bS3 += 32; };

  auto KITER = [&](int kt, int ct){
    __builtin_amdgcn_s_barrier();
    if (kt + 1 < nkt){
      STAGE(ct ^ 1); ADV();
      asm volatile("s_waitcnt vmcnt(6)" ::: "memory");
    } else {
      asm volatile("s_waitcnt vmcnt(0)" ::: "memory");
    }
    __builtin_amdgcn_sched_barrier(0);
    __builtin_amdgcn_s_barrier();
    const char* base = (const char*)sm + ct * 24576;
    s16x8 af[4], bfr[8];
    #pragma unroll
    for (int mb = 0; mb < 4; mb++) af[mb] = *(const s16x8*)(base + aOff[mb]);
    #pragma unroll
    for (int nb = 0; nb < 8; nb++) bfr[nb] = *(const s16x8*)(base + bOff[nb]);
    __builtin_amdgcn_s_setprio(1);
    #pragma unroll
    for (int mb = 0; mb < 4; mb++)
      #pragma unroll
      for (int nb = 0; nb < 8; nb++)
        acc[mb][nb] = mfma16(af[mb], bfr[nb], acc[mb][nb]);
    __builtin_amdgcn_s_setprio(0);
  };

  STAGE(0); ADV();
  for (int kt = 0; kt < nkt; kt += 2){
    KITER(kt, 0);
    KITER(kt + 1, 1);
  }

  if (z == 2){
    const float* bias = P.b2;
    int bq_ = m0 >> 11, srow0 = m0 & 2047;
    u16* Ot = sm;
    #pragma unroll
    for (int h2 = 0; h2 < 2; h2++){
      __syncthreads();
      if (wn == h2){
        #pragma unroll
        for (int mb = 0; mb < 4; mb++){
          #pragma unroll
          for (int nb = 0; nb < 8; nb++){
            int cl = nb * 16 + li;
            int rowB = wm * 64 + mb * 16 + lq * 4;
            float bcol = bias[n0 + h2 * 128 + cl];
            unsigned p01 = cvtpk(acc[mb][nb][0] + bcol, acc[mb][nb][1] + bcol);
            unsigned p23 = cvtpk(acc[mb][nb][2] + bcol, acc[mb][nb][3] + bcol);
            int ba = cl * 256 + ((rowB * 2) ^ ((cl & 7) << 4));
            *(unsigned*)((char*)Ot + ba) = p01;
            *(unsigned*)((char*)Ot + ba + 4) = p23;
          }
        }
      }
      __syncthreads();
      #pragma unroll
      for (int i = 0; i < 8; i++){
        int u = i * 256 + tid;
        int cl = u >> 4, sc = u & 15;
        int ba = cl * 256 + ((sc * 16) ^ ((cl & 7) << 4));
        u16x8 vv = *(const u16x8*)((char*)Ot + ba);
        *(u16x8*)(P.outV + (((size_t)(bq_ * 1024 + n0 + h2 * 128 + cl)) << 11) + srow0 + sc * 8) = vv;
      }
    }
    return;
  }

  if (z == 3){
    float* Xo = (kbase == 0) ? P.outX0 : P.outX1;
    #pragma unroll
    for (int mb = 0; mb < 4; mb++){
      #pragma unroll
      for (int nb = 0; nb < 8; nb++){
        int col = n0 + wn * 128 + nb * 16 + li;
        #pragma unroll
        for (int r = 0; r < 4; r++){
          int row = m0 + wm * 64 + mb * 16 + lq * 4 + r;
          Xo[(size_t)row * 1024 + col] = acc[mb][nb][r];
        }
      }
    }
    return;
  }

  const float* bias = (z == 0) ? P.b0 : P.b1;
  #pragma unroll
  for (int mb = 0; mb < 4; mb++){
    #pragma unroll
    for (int nb = 0; nb < 8; nb++){
      int colL = wn * 128 + nb * 16 + li; int col = n0 + colL;
      float bcol = bias[col];
      #pragma unroll
      for (int r = 0; r < 4; r++){
        int row = m0 + wm * 64 + mb * 16 + lq * 4 + r;
        float v = acc[mb][nb][r] + bcol;
        if (z == 0){
          P.outQ[(size_t)row * 1024 + col] = f2bf(v * CKF);
        } else {
          v += P.ctx[(size_t)(row >> 11) * 1024 + col];
          P.outK[(size_t)row * 1024 + col] = f2bf(v);
        }
      }
    }
  }
}

// ---------------------------------------------------------------- flash attention (unchanged)
__global__ __launch_bounds__(256) void attn_kernel(
    const u16* __restrict__ Qg, const u16* __restrict__ Kg, const u16* __restrict__ Vtg,
    const unsigned* __restrict__ mbits, u16* __restrict__ ctx2){
  __shared__ __align__(16) u16 arena[17408];
  int tid = threadIdx.x, lane = tid & 63, w = tid >> 6;
  int l31 = lane & 31, hi = lane >> 5;
  int r7 = l31 & 7;
  int orig = blockIdx.x + (blockIdx.y << 4);
  int swz = (orig & 7) * 64 + (orig >> 3);
  int q0 = (swz & 15) * 128, bh = swz >> 4, b = bh >> 4, h = bh & 15;

  s16x8 qf[4];
  {
    const u16* qp = Qg + (size_t)(b * 2048 + q0 + w * 32 + l31) * 1024 + h * 64 + hi * 8;
    #pragma unroll
    for (int ks = 0; ks < 4; ks++)
      qf[ks] = *(const s16x8*)(qp + ks * 16);
  }
  s16x8 onesf;
  #pragma unroll
  for (int e = 0; e < 8; e++) onesf[e] = (short)0x3F80;
  f32x16 ZERO;
  #pragma unroll
  for (int r = 0; r < 16; r++) ZERO[r] = 0.f;

  int scolS = ((lane & 7) ^ (lane >> 3)) << 3;
  int rowS = w * 16 + (lane >> 3);
  const u16* kS0 = Kg + (size_t)(b * 2048 + rowS) * 1024 + h * 64 + scolS;
  const u16* kS1 = kS0 + (size_t)8 * 1024;
  const u16* vS0 = Vtg + (((size_t)(bh * 64 + rowS)) << 11) + scolS;
  const u16* vS1 = vS0 + ((size_t)8 << 11);
  int um = w * 64 + lane;
  const unsigned* mS = mbits + (size_t)(b * 2048 + q0 + (um >> 1)) * 64 + (um & 1);
  int kD0 = w * 1024, kD1 = w * 1024 + 512;

  int qr = w * 32 + l31;
  int koff[2][4], voff[2][4];
  #pragma unroll
  for (int jj = 0; jj < 2; jj++)
    #pragma unroll
    for (int ks = 0; ks < 4; ks++){
      koff[jj][ks] = ((jj * 32 + l31) * 64 + (((ks * 2 + hi) ^ r7) << 3)) * 2;
      voff[jj][ks] = 8192 + ((jj * 32 + l31) * 64 + (((ks * 2 + hi) ^ r7) << 3)) * 2;
    }
  int mB = 32768 + qr * 8;

  auto STAGE = [&](int ct){
    u16* dst = &arena[ct * 8192];
    glds16(kS0, dst + kD0);
    glds16(kS1, dst + kD1);
    glds16(vS0, dst + 4096 + kD0);
    glds16(vS1, dst + 4096 + kD1);
    glds4(mS, (unsigned*)&arena[16384] + ct * 256 + w * 64);
  };
  auto ADV = [&](){
    kS0 += (size_t)64 * 1024; kS1 += (size_t)64 * 1024;
    vS0 += 64; vS1 += 64; mS += 2;
  };

  f32x16 accO[2], accS;
  #pragma unroll
  for (int d = 0; d < 2; d++) accO[d] = ZERO;
  accS = ZERO;

  STAGE(0); ADV();

  auto ITER = [&](int t, int ct){
    __builtin_amdgcn_s_barrier();
    if (t < 31){
      STAGE(ct ^ 1); ADV();
      asm volatile("s_waitcnt vmcnt(5)" ::: "memory");
    } else {
      asm volatile("s_waitcnt vmcnt(0)" ::: "memory");
    }
    __builtin_amdgcn_sched_barrier(0);
    __builtin_amdgcn_s_barrier();
    const char* base = (const char*)arena + ct * 16384;

    f32x16 S[2];
    __builtin_amdgcn_s_setprio(1);
    #pragma unroll
    for (int jj = 0; jj < 2; jj++){
      S[jj] = ZERO;
      #pragma unroll
      for (int ks = 0; ks < 4; ks++){
        s16x8 kf = *(const s16x8*)(base + koff[jj][ks]);
        S[jj] = mfma32(kf, qf[ks], S[jj]);
      }
    }
    __builtin_amdgcn_s_setprio(0);

    uint2v mw = *(const uint2v*)((const char*)arena + ct * 1024 + mB);
    unsigned mh0 = mw[0] >> (hi << 2), mh1 = mw[1] >> (hi << 2);
    #pragma unroll
    for (int jj = 0; jj < 2; jj++){
      unsigned mh = jj ? mh1 : mh0;
      #pragma unroll
      for (int rg = 0; rg < 16; rg++){
        int pos = (rg & 3) + ((rg >> 2) << 3);
        float pv = exp2a(S[jj][rg]);
        S[jj][rg] = ((mh >> pos) & 1u) ? pv : 0.f;
      }
    }

    s16x8 pf[4];
    #pragma unroll
    for (int jj = 0; jj < 2; jj++){
      #pragma unroll
      for (int hs = 0; hs < 2; hs++){
        int rb = hs * 8;
        unsigned A0 = cvtpk(S[jj][rb + 0], S[jj][rb + 1]);
        unsigned A1 = cvtpk(S[jj][rb + 2], S[jj][rb + 3]);
        unsigned B0 = cvtpk(S[jj][rb + 4], S[jj][rb + 5]);
        unsigned B1 = cvtpk(S[jj][rb + 6], S[jj][rb + 7]);
        uint2v r01 = __builtin_amdgcn_permlane32_swap(A0, B0, false, false);
        uint2v r23 = __builtin_amdgcn_permlane32_swap(A1, B1, false, false);
        uint4v uu = { r01[0], r23[0], r01[1], r23[1] };
        pf[jj * 2 + hs] = *(s16x8*)&uu;
      }
    }
    __builtin_amdgcn_s_setprio(1);
    #pragma unroll
    for (int c = 0; c < 4; c++){
      #pragma unroll
      for (int dh = 0; dh < 2; dh++){
        s16x8 vf = *(const s16x8*)(base + voff[dh][c]);
        accO[dh] = mfma32(vf, pf[c], accO[dh]);
      }
      accS = mfma32(onesf, pf[c], accS);
    }
    __builtin_amdgcn_s_setprio(0);
  };

  for (int t = 0; t < 32; t += 2){
    ITER(t, 0);
    ITER(t + 1, 1);
  }

  __syncthreads();
  float lsum = accS[0];
  float inv = 1.f / lsum;
  u16* Ot = arena;
  #pragma unroll
  for (int dh = 0; dh < 2; dh++){
    #pragma unroll
    for (int rg = 0; rg < 16; rg += 2){
      int dk = dh * 32 + (rg & 3) + ((rg >> 2) << 3) + (hi << 2);
      unsigned pk = cvtpk(accO[dh][rg] * inv, accO[dh][rg + 1] * inv);
      *(unsigned*)&Ot[qr * 64 + (((dk >> 3) ^ (qr & 7)) << 3) + (dk & 7)] = pk;
    }
  }
  __syncthreads();
  #pragma unroll
  for (int i = 0; i < 4; i++){
    int u = i * 256 + tid, row = u >> 3, slot = u & 7;
    u16x8 vv = *(const u16x8*)&Ot[row * 64 + ((slot ^ (row & 7)) << 3)];
    *(u16x8*)(ctx2 + (size_t)(b * 2048 + q0 + row) * 1024 + h * 64 + slot * 8) = vv;
  }
}

// ---------------------------------------------------------------- LayerNorm of (X0 + X1 + query + bo)
__global__ __launch_bounds__(256) void ln_kernel(const float* __restrict__ X0,
                                                 const float* __restrict__ X1,
                                                 const float* __restrict__ qres,
                                                 const float* __restrict__ bo,
                                                 const float* __restrict__ g,
                                                 const float* __restrict__ bb,
                                                 float* __restrict__ out){
  size_t row = blockIdx.x;
  int tid = threadIdx.x;
  float4 a = *(const float4*)(X0 + row * 1024 + tid * 4);
  float4 c = *(const float4*)(X1 + row * 1024 + tid * 4);
  float4 q = *(const float4*)(qres + row * 1024 + tid * 4);
  float4 bv = *(const float4*)(bo + tid * 4);
  float4 v;
  v.x = a.x + c.x + q.x + bv.x;
  v.y = a.y + c.y + q.y + bv.y;
  v.z = a.z + c.z + q.z + bv.z;
  v.w = a.w + c.w + q.w + bv.w;
  float s = v.x + v.y + v.z + v.w;
  float s2 = v.x*v.x + v.y*v.y + v.z*v.z + v.w*v.w;
  #pragma unroll
  for (int o = 1; o < 64; o <<= 1){
    s += __shfl_xor(s, o, 64);
    s2 += __shfl_xor(s2, o, 64);
  }
  __shared__ float rs[4], rs2[4];
  int w = tid >> 6;
  if ((tid & 63) == 0){ rs[w] = s; rs2[w] = s2; }
  __syncthreads();
  s = rs[0] + rs[1] + rs[2] + rs[3];
  s2 = rs2[0] + rs2[1] + rs2[2] + rs2[3];
  float mu = s * (1.f / 1024.f);
  float var = s2 * (1.f / 1024.f) - mu * mu;
  float rstd = rsqrtf(var + 1e-5f);
  float4 gg = *(const float4*)(g + tid * 4);
  float4 bt = *(const float4*)(bb + tid * 4);
  float4 o;
  o.x = (v.x - mu) * rstd * gg.x + bt.x;
  o.y = (v.y - mu) * rstd * gg.y + bt.y;
  o.z = (v.z - mu) * rstd * gg.z + bt.z;
  o.w = (v.w - mu) * rstd * gg.w + bt.w;
  *(float4*)(out + row * 1024 + tid * 4) = o;
}

// ----------------------------------------------------------------
extern "C" void kernel_launch(void* const* d_in, const int* in_sizes, int n_in,
                              void* d_out, int out_size, void* d_ws, size_t ws_size,
                              hipStream_t stream){
  const float* query = (const float*)d_in[0];
  const float* key_  = (const float*)d_in[1];
  const float* value = (const float*)d_in[2];
  const int*   mask  = (const int*)d_in[3];
  const float* mc    = (const float*)d_in[4];
  const float* Wq = (const float*)d_in[5];  const float* bq = (const float*)d_in[6];
  const float* Wk = (const float*)d_in[7];  const float* bk = (const float*)d_in[8];
  const float* Wv = (const float*)d_in[9];  const float* bv = (const float*)d_in[10];
  const float* Wo = (const float*)d_in[11]; const float* bo = (const float*)d_in[12];
  const float* Wc = (const float*)d_in[13]; const float* bc = (const float*)d_in[14];
  const float* lng = (const float*)d_in[15]; const float* lnb = (const float*)d_in[16];
  float* outp = (float*)d_out;
  uint8_t* ws = (uint8_t*)d_ws;
  const size_t MB = (size_t)1 << 20;
  if (ws_size < 58 * MB) return;

  u16* q_bf = (u16*)(ws + 0);         // dead after QKV; reused as ctx2
  u16* k_bf = (u16*)(ws + 8 * MB);
  u16* v_bf = (u16*)(ws + 16 * MB);
  float* X0 = (float*)(ws + 8 * MB);  // overlays k_bf/v_bf (dead after QKV GEMM)
  u16* Qb   = (u16*)(ws + 24 * MB);
  u16* Kb   = (u16*)(ws + 32 * MB);
  float* X1 = (float*)(ws + 32 * MB); // overlays Kb/Vt (dead after attn)
  u16* Vt   = (u16*)(ws + 40 * MB);
  u16* Wqt  = (u16*)(ws + 48 * MB);
  u16* Wkt  = (u16*)(ws + 50 * MB);
  u16* Wvt  = (u16*)(ws + 52 * MB);
  u16* Wot  = (u16*)(ws + 54 * MB);
  unsigned* mbits = (unsigned*)(ws + 56 * MB);
  float* ctxf = (float*)(ws + 57 * MB);                  // 8 KB
  float* ctxpart = (float*)(ws + 57 * MB + 65536);       // 128 KB (16 slices x 2 x 1024 f32)
  u16* ctx2 = q_bf;

  PrepParams PP;
  PP.q = query; PP.k = key_; PP.v = value; PP.mask = mask; PP.mc = mc;
  PP.W0 = Wq; PP.W1 = Wk; PP.W2 = Wv; PP.W3 = Wo; PP.Wc = Wc;
  PP.qo = q_bf; PP.ko = k_bf; PP.vo = v_bf;
  PP.T0 = Wqt; PP.T1 = Wkt; PP.T2 = Wvt; PP.T3 = Wot;
  PP.bits = mbits; PP.part = ctxpart;
  prep_kernel<<<43024, 256, 0, stream>>>(PP);

  ctxred_kernel<<<2, 256, 0, stream>>>(ctxpart, bc, ctxf);

  GemmParams gp;
  gp.A0 = q_bf; gp.A1 = k_bf; gp.A2 = v_bf; gp.A3 = ctx2;
  gp.W0 = Wqt;  gp.W1 = Wkt;  gp.W2 = Wvt;  gp.W3 = Wot;
  gp.b0 = bq;   gp.b1 = bk;   gp.b2 = bv;
  gp.ctx = ctxf;
  gp.outQ = Qb; gp.outK = Kb; gp.outV = Vt; gp.outX0 = X0; gp.outX1 = X1;
  gp.which = -1;
  gemm_kernel<<<dim3(4, 32, 3), 256, 0, stream>>>(gp);

  attn_kernel<<<dim3(16, 32), 256, 0, stream>>>(Qb, Kb, Vt, mbits, ctx2);

  gp.which = 3;
  gemm_kernel<<<dim3(4, 32, 2), 256, 0, stream>>>(gp);

  ln_kernel<<<4096, 256, 0, stream>>>(X0, X1, query, bo, lng, lnb, outp);
}

// Round 13
// 160.892 us; speedup vs baseline: 1.3662x; 1.0011x over previous
//
#include <hip/hip_runtime.h>
#include <cstdint>

typedef unsigned short u16;
typedef __attribute__((ext_vector_type(8))) short s16x8;
typedef __attribute__((ext_vector_type(8))) unsigned short u16x8;
typedef __attribute__((ext_vector_type(4))) float f32x4;
typedef __attribute__((ext_vector_type(16))) float f32x16;
typedef __attribute__((ext_vector_type(2))) unsigned uint2v;
typedef __attribute__((ext_vector_type(4))) unsigned uint4v;

#define CKF 0.18033688011f  // log2(e)/8, folded into Q projection

__device__ inline u16 f2bf(float f){
  union { float f; uint32_t u; } v; v.f = f;
  uint32_t r = v.u + 0x7fffu + ((v.u >> 16) & 1u);
  return (u16)(r >> 16);
}

__device__ inline f32x4 mfma16(s16x8 a, s16x8 b, f32x4 c){
  return __builtin_amdgcn_mfma_f32_16x16x32_bf16(a, b, c, 0, 0, 0);
}
__device__ inline f32x16 mfma32(s16x8 a, s16x8 b, f32x16 c){
  return __builtin_amdgcn_mfma_f32_32x32x16_bf16(a, b, c, 0, 0, 0);
}
__device__ inline unsigned cvtpk(float a, float b){
  unsigned r;
  asm("v_cvt_pk_bf16_f32 %0, %1, %2" : "=v"(r) : "v"(a), "v"(b));
  return r;
}
__device__ inline float exp2a(float x){
  float r;
  asm("v_exp_f32 %0, %1" : "=v"(r) : "v"(x));
  return r;
}
__device__ inline void glds16(const u16* g, u16* l){
  __builtin_amdgcn_global_load_lds((const __attribute__((address_space(1))) void*)g,
                                   (__attribute__((address_space(3))) void*)l, 16, 0, 0);
}
__device__ inline void glds4(const unsigned* g, unsigned* l){
  __builtin_amdgcn_global_load_lds((const __attribute__((address_space(1))) void*)g,
                                   (__attribute__((address_space(3))) void*)l, 4, 0, 0);
}

// ---------------------------------------------------------------- merged prep (R11, unchanged)
struct PrepParams {
  const float* q; const float* k; const float* v;
  const int* mask; const float* mc;
  const float* W0; const float* W1; const float* W2; const float* W3;
  const float* Wc;
  u16* qo; u16* ko; u16* vo;
  u16* T0; u16* T1; u16* T2; u16* T3;
  unsigned* bits; float* part;
};

__global__ __launch_bounds__(256) void prep_kernel(PrepParams PP){
  __shared__ float shf[1056];
  int blk = blockIdx.x, tid = threadIdx.x;
  if (blk < 6144){
    int byy = blk >> 11, bxx = blk & 2047;
    const float* src = (byy == 0) ? PP.q : (byy == 1) ? PP.k : PP.v;
    u16* dst = (byy == 0) ? PP.qo : (byy == 1) ? PP.ko : PP.vo;
    size_t i = ((size_t)bxx * 256 + tid) * 8;
    float4 a = *(const float4*)(src + i);
    float4 b = *(const float4*)(src + i + 4);
    u16x8 o = { f2bf(a.x), f2bf(a.y), f2bf(a.z), f2bf(a.w),
                f2bf(b.x), f2bf(b.y), f2bf(b.z), f2bf(b.w) };
    *(u16x8*)(dst + i) = o;
  } else if (blk < 10240){
    int idx = blk - 6144;
    int bxx = idx & 31, byy = (idx >> 5) & 31, bzz = idx >> 10;
    const float* W = (bzz == 0) ? PP.W0 : (bzz == 1) ? PP.W1 : (bzz == 2) ? PP.W2 : PP.W3;
    u16* T = (bzz == 0) ? PP.T0 : (bzz == 1) ? PP.T1 : (bzz == 2) ? PP.T2 : PP.T3;
    float (*t)[33] = (float(*)[33])shf;
    int n0 = bxx * 32, k0 = byy * 32;
    int tx = tid & 31, ty = tid >> 5;
    #pragma unroll
    for (int j = 0; j < 4; j++)
      t[ty + j*8][tx] = W[(size_t)(k0 + ty + j*8) * 1024 + n0 + tx];
    __syncthreads();
    #pragma unroll
    for (int j = 0; j < 4; j++)
      T[(size_t)(n0 + ty + j*8) * 1024 + k0 + tx] = f2bf(t[tx][ty + j*8]);
  } else if (blk < 43008){
    size_t i = (size_t)(blk - 10240) * 256 + tid;
    int v = PP.mask[i];
    unsigned long long bal = __ballot(v != 0);
    int lane = tid & 63;
    if (lane == 0)       PP.bits[i >> 5] = (unsigned)bal;
    else if (lane == 32) PP.bits[i >> 5] = (unsigned)(bal >> 32);
  } else {
    int slice = blk - 43008;          // 0..15
    int k0 = slice * 64;
    float4 a0 = {0.f,0.f,0.f,0.f}, a1 = {0.f,0.f,0.f,0.f};
    const float* wp = PP.Wc + (size_t)k0 * 1024 + tid * 4;
    #pragma unroll 8
    for (int k = 0; k < 64; k++){
      float4 wv = *(const float4*)(wp + (size_t)k * 1024);
      float m0 = PP.mc[k0 + k], m1 = PP.mc[1024 + k0 + k];
      a0.x += m0 * wv.x; a0.y += m0 * wv.y; a0.z += m0 * wv.z; a0.w += m0 * wv.w;
      a1.x += m1 * wv.x; a1.y += m1 * wv.y; a1.z += m1 * wv.z; a1.w += m1 * wv.w;
    }
    *(float4*)(PP.part + ((size_t)slice * 2 + 0) * 1024 + tid * 4) = a0;
    *(float4*)(PP.part + ((size_t)slice * 2 + 1) * 1024 + tid * 4) = a1;
  }
}

__global__ __launch_bounds__(256) void ctxred_kernel(const float* __restrict__ part,
                                                     const float* __restrict__ bc,
                                                     float* __restrict__ ctx){
  int b = blockIdx.x, tid = threadIdx.x;
  float4 s = *(const float4*)(bc + tid * 4);
  #pragma unroll 4
  for (int sl = 0; sl < 16; sl++){
    float4 p = *(const float4*)(part + ((size_t)sl * 2 + b) * 1024 + tid * 4);
    s.x += p.x; s.y += p.y; s.z += p.z; s.w += p.w;
  }
  *(float4*)(ctx + (size_t)b * 1024 + tid * 4) = s;
}

// ---------------------------------------------------------------- GEMM (R8 exact: BM=128 BN=128 BK=32)
struct GemmParams {
  const u16* A0; const u16* A1; const u16* A2; const u16* A3;
  const u16* W0; const u16* W1; const u16* W2; const u16* W3;
  const float* b0; const float* b1; const float* b2;
  const float* ctx;
  u16* outQ; u16* outK; u16* outV; float* outX0; float* outX1;
  int which;
};

__global__ __launch_bounds__(256) void gemm_kernel(GemmParams P){
  int o = blockIdx.x + (blockIdx.y << 3) + (blockIdx.z << 8);
  int xcd = o & 7, j = o >> 3;
  int by = xcd + ((j & 3) << 3);
  int bx = (j >> 2) & 7;
  int bz = j >> 5;

  int z, kbase, nkt;
  const u16* A; const u16* W;
  if (P.which < 0){
    z = bz; kbase = 0; nkt = 32;
    if (z == 0){ A = P.A0; W = P.W0; }
    else if (z == 1){ A = P.A1; W = P.W1; }
    else { A = P.A2; W = P.W2; }
  } else {
    z = 3; kbase = bz * 512; nkt = 16;
    A = P.A3; W = P.W3;
  }
  int m0 = by * 128, n0 = bx * 128;
  __shared__ __align__(16) u16 sm[16384];
  int tid = threadIdx.x, lane = tid & 63, w = tid >> 6;
  int li = lane & 15, lq = lane >> 4;
  int wm = w >> 1, wn = w & 1;
  f32x4 zero = {0.f, 0.f, 0.f, 0.f};
  f32x4 acc[4][4];
  #pragma unroll
  for (int i = 0; i < 4; i++)
    #pragma unroll
    for (int jj = 0; jj < 4; jj++) acc[i][jj] = zero;

  int scolS = ((lane & 3) ^ ((lane >> 3) & 3)) << 3;
  int row0 = w * 16 + (lane >> 2);
  const u16* aS0 = A + (size_t)(m0 + row0) * 1024 + kbase + scolS;
  const u16* aS1 = aS0 + (size_t)64 * 1024;
  const u16* bS0 = W + (size_t)(n0 + row0) * 1024 + kbase + scolS;
  const u16* bS1 = bS0 + (size_t)64 * 1024;
  int aD0 = (w * 64) * 8, aD1 = (256 + w * 64) * 8;

  int aOff[4], bOff[4];
  #pragma unroll
  for (int mb = 0; mb < 4; mb++){
    int row = wm * 64 + mb * 16 + li;
    aOff[mb] = (row * 32 + ((lq ^ ((row >> 1) & 3)) << 3)) * 2;
  }
  #pragma unroll
  for (int nb = 0; nb < 4; nb++){
    int row = wn * 64 + nb * 16 + li;
    bOff[nb] = 8192 + (row * 32 + ((lq ^ ((row >> 1) & 3)) << 3)) * 2;
  }

  auto STAGE = [&](int ct){
    u16* Ab = &sm[ct * 8192];
    u16* Bb = &sm[ct * 8192 + 4096];
    glds16(aS0, Ab + aD0);
    glds16(aS1, Ab + aD1);
    glds16(bS0, Bb + aD0);
    glds16(bS1, Bb + aD1);
  };
  auto ADV = [&](){ aS0 += 32; aS1 += 32; bS0 += 32; bS1 += 32; };

  auto KITER = [&](int kt, int ct){
    __builtin_amdgcn_s_barrier();
    if (kt + 1 < nkt){
      STAGE(ct ^ 1); ADV();
      asm volatile("s_waitcnt vmcnt(4)" ::: "memory");
    } else {
      asm volatile("s_waitcnt vmcnt(0)" ::: "memory");
    }
    __builtin_amdgcn_sched_barrier(0);
    __builtin_amdgcn_s_barrier();
    const char* base = (const char*)sm + ct * 16384;
    s16x8 af[4], bfr[4];
    #pragma unroll
    for (int mb = 0; mb < 4; mb++) af[mb] = *(const s16x8*)(base + aOff[mb]);
    #pragma unroll
    for (int nb = 0; nb < 4; nb++) bfr[nb] = *(const s16x8*)(base + bOff[nb]);
    __builtin_amdgcn_s_setprio(1);
    #pragma unroll
    for (int mb = 0; mb < 4; mb++)
      #pragma unroll
      for (int nb = 0; nb < 4; nb++)
        acc[mb][nb] = mfma16(af[mb], bfr[nb], acc[mb][nb]);
    __builtin_amdgcn_s_setprio(0);
  };

  STAGE(0); ADV();
  for (int kt = 0; kt < nkt; kt += 2){
    KITER(kt, 0);
    KITER(kt + 1, 1);
  }

  if (z == 2){
    const float* bias = P.b2;
    __syncthreads();
    u16* Ot = sm;
    #pragma unroll
    for (int mb = 0; mb < 4; mb++){
      #pragma unroll
      for (int nb = 0; nb < 4; nb++){
        int colL = wn * 64 + nb * 16 + li;
        int rowB = wm * 64 + mb * 16 + lq * 4;
        float bcol = bias[n0 + colL];
        unsigned p01 = cvtpk(acc[mb][nb][0] + bcol, acc[mb][nb][1] + bcol);
        unsigned p23 = cvtpk(acc[mb][nb][2] + bcol, acc[mb][nb][3] + bcol);
        int ba = colL * 256 + ((rowB * 2) ^ ((colL & 7) << 4));
        *(unsigned*)((char*)Ot + ba) = p01;
        *(unsigned*)((char*)Ot + ba + 4) = p23;
      }
    }
    __syncthreads();
    int bq_ = m0 >> 11, srow0 = m0 & 2047;
    #pragma unroll
    for (int i = 0; i < 8; i++){
      int u = i * 256 + tid;
      int colL = u >> 4, sc = u & 15;
      int ba = colL * 256 + ((sc * 16) ^ ((colL & 7) << 4));
      u16x8 vv = *(const u16x8*)((char*)Ot + ba);
      *(u16x8*)(P.outV + (((size_t)(bq_ * 1024 + n0 + colL)) << 11) + srow0 + sc * 8) = vv;
    }
    return;
  }

  if (z == 3){
    float* Xo = (kbase == 0) ? P.outX0 : P.outX1;
    #pragma unroll
    for (int mb = 0; mb < 4; mb++){
      #pragma unroll
      for (int nb = 0; nb < 4; nb++){
        int col = n0 + wn * 64 + nb * 16 + li;
        #pragma unroll
        for (int r = 0; r < 4; r++){
          int row = m0 + wm * 64 + mb * 16 + lq * 4 + r;
          Xo[(size_t)row * 1024 + col] = acc[mb][nb][r];
        }
      }
    }
    return;
  }

  const float* bias = (z == 0) ? P.b0 : P.b1;
  #pragma unroll
  for (int mb = 0; mb < 4; mb++){
    #pragma unroll
    for (int nb = 0; nb < 4; nb++){
      int colL = wn * 64 + nb * 16 + li; int col = n0 + colL;
      float bcol = bias[col];
      #pragma unroll
      for (int r = 0; r < 4; r++){
        int row = m0 + wm * 64 + mb * 16 + lq * 4 + r;
        float v = acc[mb][nb][r] + bcol;
        if (z == 0){
          P.outQ[(size_t)row * 1024 + col] = f2bf(v * CKF);
        } else {
          v += P.ctx[(size_t)(row >> 11) * 1024 + col];
          P.outK[(size_t)row * 1024 + col] = f2bf(v);
        }
      }
    }
  }
}

// ---------------------------------------------------------------- flash attention: 8 waves (512 thr),
// 4 q-waves x 2 kv-parity groups; per-parity private dbuf KVBLK=64; static softmax -> merge = add.
// FIX vs R12: compute-read base uses p*32768 (buf (p,ct) at byte p*32768 + ct*16384).
__global__ __launch_bounds__(512) void attn_kernel(
    const u16* __restrict__ Qg, const u16* __restrict__ Kg, const u16* __restrict__ Vtg,
    const unsigned* __restrict__ mbits, u16* __restrict__ ctx2){
  __shared__ __align__(16) u16 arena[36864];
  int tid = threadIdx.x, lane = tid & 63, w = tid >> 6;
  int qw = w & 3, p = w >> 2;
  int l31 = lane & 31, hi = lane >> 5;
  int r7 = l31 & 7;
  int orig = blockIdx.x + (blockIdx.y << 4);
  int swz = (orig & 7) * 64 + (orig >> 3);
  int q0 = (swz & 15) * 128, bh = swz >> 4, b = bh >> 4, h = bh & 15;
  int qr = qw * 32 + l31;

  s16x8 qf[4];
  {
    const u16* qp = Qg + (size_t)(b * 2048 + q0 + qr) * 1024 + h * 64 + hi * 8;
    #pragma unroll
    for (int ks = 0; ks < 4; ks++)
      qf[ks] = *(const s16x8*)(qp + ks * 16);
  }
  s16x8 onesf;
  #pragma unroll
  for (int e = 0; e < 8; e++) onesf[e] = (short)0x3F80;
  f32x16 ZERO;
  #pragma unroll
  for (int r = 0; r < 16; r++) ZERO[r] = 0.f;

  int scolS = ((lane & 7) ^ (lane >> 3)) << 3;
  int rowS = qw * 16 + (lane >> 3);
  const u16* kS0 = Kg + (size_t)(b * 2048 + p * 64 + rowS) * 1024 + h * 64 + scolS;
  const u16* kS1 = kS0 + (size_t)8 * 1024;
  const u16* vS0 = Vtg + (((size_t)(bh * 64 + rowS)) << 11) + p * 64 + scolS;
  const u16* vS1 = vS0 + ((size_t)8 << 11);
  int um = qw * 64 + lane;
  const unsigned* mS = mbits + (size_t)(b * 2048 + q0 + (um >> 1)) * 64 + p * 2 + (um & 1);
  int kD0 = qw * 1024, kD1 = qw * 1024 + 512;

  int koff[2][4], voff[2][4];
  #pragma unroll
  for (int jj = 0; jj < 2; jj++)
    #pragma unroll
    for (int ks = 0; ks < 4; ks++){
      koff[jj][ks] = ((jj * 32 + l31) * 64 + (((ks * 2 + hi) ^ r7) << 3)) * 2;
      voff[jj][ks] = 8192 + ((jj * 32 + l31) * 64 + (((ks * 2 + hi) ^ r7) << 3)) * 2;
    }
  const char* baseP = (const char*)arena + p * 32768;           // FIX: was p*16384
  int mBp = 65536 + p * 2048 + qr * 8;                           // +ct*1024

  auto STAGE = [&](int ct){
    u16* dst = &arena[(p * 2 + ct) * 8192];
    glds16(kS0, dst + kD0);
    glds16(kS1, dst + kD1);
    glds16(vS0, dst + 4096 + kD0);
    glds16(vS1, dst + 4096 + kD1);
    glds4(mS, (unsigned*)&arena[32768] + (p * 2 + ct) * 256 + qw * 64);
  };
  auto ADV = [&](){
    kS0 += (size_t)128 * 1024; kS1 += (size_t)128 * 1024;
    vS0 += 128; vS1 += 128; mS += 4;
  };

  f32x16 accO[2], accS;
  #pragma unroll
  for (int d = 0; d < 2; d++) accO[d] = ZERO;
  accS = ZERO;

  STAGE(0); ADV();

  auto ITER = [&](int jt, int ct){
    __builtin_amdgcn_s_barrier();
    if (jt < 15){
      STAGE(ct ^ 1); ADV();
      asm volatile("s_waitcnt vmcnt(5)" ::: "memory");
    } else {
      asm volatile("s_waitcnt vmcnt(0)" ::: "memory");
    }
    __builtin_amdgcn_sched_barrier(0);
    __builtin_amdgcn_s_barrier();
    const char* base = baseP + ct * 16384;

    f32x16 S[2];
    __builtin_amdgcn_s_setprio(1);
    #pragma unroll
    for (int jj = 0; jj < 2; jj++){
      S[jj] = ZERO;
      #pragma unroll
      for (int ks = 0; ks < 4; ks++){
        s16x8 kf = *(const s16x8*)(base + koff[jj][ks]);
        S[jj] = mfma32(kf, qf[ks], S[jj]);
      }
    }
    __builtin_amdgcn_s_setprio(0);

    uint2v mw = *(const uint2v*)((const char*)arena + mBp + ct * 1024);
    unsigned mh0 = mw[0] >> (hi << 2), mh1 = mw[1] >> (hi << 2);
    #pragma unroll
    for (int jj = 0; jj < 2; jj++){
      unsigned mh = jj ? mh1 : mh0;
      #pragma unroll
      for (int rg = 0; rg < 16; rg++){
        int pos = (rg & 3) + ((rg >> 2) << 3);
        float pv = exp2a(S[jj][rg]);
        S[jj][rg] = ((mh >> pos) & 1u) ? pv : 0.f;
      }
    }

    s16x8 pf[4];
    #pragma unroll
    for (int jj = 0; jj < 2; jj++){
      #pragma unroll
      for (int hs = 0; hs < 2; hs++){
        int rb = hs * 8;
        unsigned A0 = cvtpk(S[jj][rb + 0], S[jj][rb + 1]);
        unsigned A1 = cvtpk(S[jj][rb + 2], S[jj][rb + 3]);
        unsigned B0 = cvtpk(S[jj][rb + 4], S[jj][rb + 5]);
        unsigned B1 = cvtpk(S[jj][rb + 6], S[jj][rb + 7]);
        uint2v r01 = __builtin_amdgcn_permlane32_swap(A0, B0, false, false);
        uint2v r23 = __builtin_amdgcn_permlane32_swap(A1, B1, false, false);
        uint4v uu = { r01[0], r23[0], r01[1], r23[1] };
        pf[jj * 2 + hs] = *(s16x8*)&uu;
      }
    }
    __builtin_amdgcn_s_setprio(1);
    #pragma unroll
    for (int c = 0; c < 4; c++){
      #pragma unroll
      for (int dh = 0; dh < 2; dh++){
        s16x8 vf = *(const s16x8*)(base + voff[dh][c]);
        accO[dh] = mfma32(vf, pf[c], accO[dh]);
      }
      accS = mfma32(onesf, pf[c], accS);
    }
    __builtin_amdgcn_s_setprio(0);
  };

  for (int jt = 0; jt < 16; jt += 2){
    ITER(jt, 0);
    ITER(jt + 1, 1);
  }

  // parity merge (pure add: static softmax) then normalize + transpose + store
  __syncthreads();
  float lsum = accS[0];
  float* mg = (float*)arena;                 // [256 lanes][33] floats
  int li33 = (qw * 64 + lane) * 33;
  if (p == 1){
    #pragma unroll
    for (int dh = 0; dh < 2; dh++)
      #pragma unroll
      for (int rg = 0; rg < 16; rg++)
        mg[li33 + dh * 16 + rg] = accO[dh][rg];
    mg[li33 + 32] = lsum;
  }
  __syncthreads();
  u16* Ot = &arena[28672];
  if (p == 0){
    #pragma unroll
    for (int dh = 0; dh < 2; dh++)
      #pragma unroll
      for (int rg = 0; rg < 16; rg++)
        accO[dh][rg] += mg[li33 + dh * 16 + rg];
    lsum += mg[li33 + 32];
    float inv = 1.f / lsum;
    #pragma unroll
    for (int dh = 0; dh < 2; dh++){
      #pragma unroll
      for (int rg = 0; rg < 16; rg += 2){
        int dk = dh * 32 + (rg & 3) + ((rg >> 2) << 3) + (hi << 2);
        unsigned pk = cvtpk(accO[dh][rg] * inv, accO[dh][rg + 1] * inv);
        *(unsigned*)&Ot[qr * 64 + (((dk >> 3) ^ (qr & 7)) << 3) + (dk & 7)] = pk;
      }
    }
  }
  __syncthreads();
  #pragma unroll
  for (int i = 0; i < 2; i++){
    int u = i * 512 + tid, row = u >> 3, slot = u & 7;
    u16x8 vv = *(const u16x8*)&Ot[row * 64 + ((slot ^ (row & 7)) << 3)];
    *(u16x8*)(ctx2 + (size_t)(b * 2048 + q0 + row) * 1024 + h * 64 + slot * 8) = vv;
  }
}

// ---------------------------------------------------------------- LayerNorm of (X0 + X1 + query + bo)
__global__ __launch_bounds__(256) void ln_kernel(const float* __restrict__ X0,
                                                 const float* __restrict__ X1,
                                                 const float* __restrict__ qres,
                                                 const float* __restrict__ bo,
                                                 const float* __restrict__ g,
                                                 const float* __restrict__ bb,
                                                 float* __restrict__ out){
  size_t row = blockIdx.x;
  int tid = threadIdx.x;
  float4 a = *(const float4*)(X0 + row * 1024 + tid * 4);
  float4 c = *(const float4*)(X1 + row * 1024 + tid * 4);
  float4 q = *(const float4*)(qres + row * 1024 + tid * 4);
  float4 bv = *(const float4*)(bo + tid * 4);
  float4 v;
  v.x = a.x + c.x + q.x + bv.x;
  v.y = a.y + c.y + q.y + bv.y;
  v.z = a.z + c.z + q.z + bv.z;
  v.w = a.w + c.w + q.w + bv.w;
  float s = v.x + v.y + v.z + v.w;
  float s2 = v.x*v.x + v.y*v.y + v.z*v.z + v.w*v.w;
  #pragma unroll
  for (int o = 1; o < 64; o <<= 1){
    s += __shfl_xor(s, o, 64);
    s2 += __shfl_xor(s2, o, 64);
  }
  __shared__ float rs[4], rs2[4];
  int w = tid >> 6;
  if ((tid & 63) == 0){ rs[w] = s; rs2[w] = s2; }
  __syncthreads();
  s = rs[0] + rs[1] + rs[2] + rs[3];
  s2 = rs2[0] + rs2[1] + rs2[2] + rs2[3];
  float mu = s * (1.f / 1024.f);
  float var = s2 * (1.f / 1024.f) - mu * mu;
  float rstd = rsqrtf(var + 1e-5f);
  float4 gg = *(const float4*)(g + tid * 4);
  float4 bt = *(const float4*)(bb + tid * 4);
  float4 o;
  o.x = (v.x - mu) * rstd * gg.x + bt.x;
  o.y = (v.y - mu) * rstd * gg.y + bt.y;
  o.z = (v.z - mu) * rstd * gg.z + bt.z;
  o.w = (v.w - mu) * rstd * gg.w + bt.w;
  *(float4*)(out + row * 1024 + tid * 4) = o;
}

// ----------------------------------------------------------------
extern "C" void kernel_launch(void* const* d_in, const int* in_sizes, int n_in,
                              void* d_out, int out_size, void* d_ws, size_t ws_size,
                              hipStream_t stream){
  const float* query = (const float*)d_in[0];
  const float* key_  = (const float*)d_in[1];
  const float* value = (const float*)d_in[2];
  const int*   mask  = (const int*)d_in[3];
  const float* mc    = (const float*)d_in[4];
  const float* Wq = (const float*)d_in[5];  const float* bq = (const float*)d_in[6];
  const float* Wk = (const float*)d_in[7];  const float* bk = (const float*)d_in[8];
  const float* Wv = (const float*)d_in[9];  const float* bv = (const float*)d_in[10];
  const float* Wo = (const float*)d_in[11]; const float* bo = (const float*)d_in[12];
  const float* Wc = (const float*)d_in[13]; const float* bc = (const float*)d_in[14];
  const float* lng = (const float*)d_in[15]; const float* lnb = (const float*)d_in[16];
  float* outp = (float*)d_out;
  uint8_t* ws = (uint8_t*)d_ws;
  const size_t MB = (size_t)1 << 20;
  if (ws_size < 58 * MB) return;

  u16* q_bf = (u16*)(ws + 0);         // dead after QKV; reused as ctx2
  u16* k_bf = (u16*)(ws + 8 * MB);
  u16* v_bf = (u16*)(ws + 16 * MB);
  float* X0 = (float*)(ws + 8 * MB);  // overlays k_bf/v_bf (dead after QKV GEMM)
  u16* Qb   = (u16*)(ws + 24 * MB);
  u16* Kb   = (u16*)(ws + 32 * MB);
  float* X1 = (float*)(ws + 32 * MB); // overlays Kb/Vt (dead after attn)
  u16* Vt   = (u16*)(ws + 40 * MB);
  u16* Wqt  = (u16*)(ws + 48 * MB);
  u16* Wkt  = (u16*)(ws + 50 * MB);
  u16* Wvt  = (u16*)(ws + 52 * MB);
  u16* Wot  = (u16*)(ws + 54 * MB);
  unsigned* mbits = (unsigned*)(ws + 56 * MB);
  float* ctxf = (float*)(ws + 57 * MB);
  float* ctxpart = (float*)(ws + 57 * MB + 65536);
  u16* ctx2 = q_bf;

  PrepParams PP;
  PP.q = query; PP.k = key_; PP.v = value; PP.mask = mask; PP.mc = mc;
  PP.W0 = Wq; PP.W1 = Wk; PP.W2 = Wv; PP.W3 = Wo; PP.Wc = Wc;
  PP.qo = q_bf; PP.ko = k_bf; PP.vo = v_bf;
  PP.T0 = Wqt; PP.T1 = Wkt; PP.T2 = Wvt; PP.T3 = Wot;
  PP.bits = mbits; PP.part = ctxpart;
  prep_kernel<<<43024, 256, 0, stream>>>(PP);

  ctxred_kernel<<<2, 256, 0, stream>>>(ctxpart, bc, ctxf);

  GemmParams gp;
  gp.A0 = q_bf; gp.A1 = k_bf; gp.A2 = v_bf; gp.A3 = ctx2;
  gp.W0 = Wqt;  gp.W1 = Wkt;  gp.W2 = Wvt;  gp.W3 = Wot;
  gp.b0 = bq;   gp.b1 = bk;   gp.b2 = bv;
  gp.ctx = ctxf;
  gp.outQ = Qb; gp.outK = Kb; gp.outV = Vt; gp.outX0 = X0; gp.outX1 = X1;
  gp.which = -1;
  gemm_kernel<<<dim3(8, 32, 3), 256, 0, stream>>>(gp);

  attn_kernel<<<dim3(16, 32), 512, 0, stream>>>(Qb, Kb, Vt, mbits, ctx2);

  gp.which = 3;
  gemm_kernel<<<dim3(8, 32, 2), 256, 0, stream>>>(gp);

  ln_kernel<<<4096, 256, 0, stream>>>(X0, X1, query, bo, lng, lnb, outp);
}